// Round 12
// baseline (321.573 us; speedup 1.0000x reference)
//
#include <hip/hip_runtime.h>
#include <hip/hip_cooperative_groups.h>
#include <stdint.h>

// PersonalMed on MI355X. B=48,V=16,M=32,C=48,CM=8,D=128,OUT=256. f32 in/out.
// Round-12: ONE cooperative kernel (grid 256x512) with grid.sync() phases:
//   A1 convert (GRU weights f32->bf16 with gate-scales folded; emb tables bf16)
//   A2 bags (bf16 gathers: mon 201MB, visit 28MB) + weight/age linears
//   B  GRU phase-0 (240 blocks, r6/r11 verified core)
//   C  GRU phase-1 (21 blocks)
//   D  final projection (24 blocks x 2 rows)
// Kills 3 dispatch boundaries + halves bag traffic; gate-scale folding deletes
// 3 muls/row/step. GRU core byte-equivalent to r11's 44.7us phase-0.
// Ledger: fold>256 blocks serializes (r9/r10); >1 chain/wave ~2x step (r7/r8);
// pre-barrier work paid xT (r9); IEEE-div gates were the old 60us floor (r6).

namespace cg = cooperative_groups;

typedef unsigned short u16;
typedef uint32_t u32;
typedef short bf8 __attribute__((ext_vector_type(8)));   // 8 bf16 = 4 VGPRs
typedef float f4 __attribute__((ext_vector_type(4)));

static __device__ __forceinline__ float bf2f(u16 b){ u32 u=((u32)b)<<16; float f; __builtin_memcpy(&f,&u,4); return f; }
static __device__ __forceinline__ u16 f2bf(float f){ u32 u; __builtin_memcpy(&u,&f,4); u32 r=(u+0x7fffu+((u>>16)&1u))>>16; return (u16)r; }
static __device__ __forceinline__ float bflo(u32 u){ u32 x=u<<16; float f; __builtin_memcpy(&f,&x,4); return f; }
static __device__ __forceinline__ float bfhi(u32 u){ u32 x=u&0xffff0000u; float f; __builtin_memcpy(&f,&x,4); return f; }
static __device__ __forceinline__ f4 mfma16(bf8 a, bf8 b, f4 c){ return __builtin_amdgcn_mfma_f32_16x16x32_bf16(a,b,c,0,0,0); }

#if __has_builtin(__builtin_amdgcn_exp2f)
static __device__ __forceinline__ float fexp2(float x){ return __builtin_amdgcn_exp2f(x); }
#else
static __device__ __forceinline__ float fexp2(float x){ float r; asm volatile("v_exp_f32 %0, %1" : "=v"(r) : "v"(x)); return r; }
#endif
#if __has_builtin(__builtin_amdgcn_rcpf)
static __device__ __forceinline__ float frcp(float x){ return __builtin_amdgcn_rcpf(x); }
#else
static __device__ __forceinline__ float frcp(float x){ float r; asm volatile("v_rcp_f32 %0, %1" : "=v"(r) : "v"(x)); return r; }
#endif
#define LOG2E 1.44269504089f
#define TWOL  2.88539008178f

struct P {
  const int *vids, *mids;
  const float *embv, *embm, *wv, *av, *ww, *wb, *aw, *ab;
  const float *mWih_f, *mWhh_f, *vWih_f, *vWhh_f;
  const float *mbih, *mbhh, *vbih, *vbhh, *fcw, *fcb;
  float* out;
  u16 *mWih_b, *mWhh_b, *vWih_b, *vWhh_b, *embm_b, *embv_b;
  u16 *mon_xT, *vis_org, *hin2T, *h2;
};

// ---------------- GRU core (r11-verified schedule + folded gate scales) ----------------
#define BARRIER() asm volatile("s_waitcnt lgkmcnt(0)\n\ts_barrier" ::: "memory")
#define HL(b_,r_,c_) hl[(b_)*2112 + (r_)*132 + (c_)]

#define ALOAD(S, tt) { int t_=(tt); if (t_>=T) t_=0; \
  const u16* p_ = ap + (size_t)t_*rstride; \
  S[0]=*(const bf8*)(p_); S[1]=*(const bf8*)(p_+32); \
  S[2]=*(const bf8*)(p_+64); S[3]=*(const bf8*)(p_+96); }

// weights pre-scaled: r/z rows by -log2e, n rows by 2log2e. G0/G1 = -L*(pre_r/z),
// G2 = 2L*gi_n part; biases scaled in prologue to match.
#define GIMM(G0,G1,G2,S) { \
  f4 t0_={bs0_,bs0_,bs0_,bs0_}; G0=t0_; \
  f4 t1_={bs1_,bs1_,bs1_,bs1_}; G1=t1_; \
  f4 t2_={bin_,bin_,bin_,bin_}; G2=t2_; \
  G0=mfma16(S[0],wfi[0][0],G0); G0=mfma16(S[1],wfi[0][1],G0); \
  G0=mfma16(S[2],wfi[0][2],G0); G0=mfma16(S[3],wfi[0][3],G0); \
  G1=mfma16(S[0],wfi[1][0],G1); G1=mfma16(S[1],wfi[1][1],G1); \
  G1=mfma16(S[2],wfi[1][2],G1); G1=mfma16(S[3],wfi[1][3],G1); \
  G2=mfma16(S[0],wfi[2][0],G2); G2=mfma16(S[1],wfi[2][1],G2); \
  G2=mfma16(S[2],wfi[2][2],G2); G2=mfma16(S[3],wfi[2][3],G2); }

#define GH(G0,G1,AN) { \
  bf8 hf0_=*(const bf8*)&HL(cur,lr,lq*8); \
  bf8 hf1_=*(const bf8*)&HL(cur,lr,32+lq*8); \
  bf8 hf2_=*(const bf8*)&HL(cur,lr,64+lq*8); \
  bf8 hf3_=*(const bf8*)&HL(cur,lr,96+lq*8); \
  f4 an_={bhn_,bhn_,bhn_,bhn_}; AN=an_; \
  G0=mfma16(hf0_,wfh[0][0],G0); G0=mfma16(hf1_,wfh[0][1],G0); \
  G0=mfma16(hf2_,wfh[0][2],G0); G0=mfma16(hf3_,wfh[0][3],G0); \
  G1=mfma16(hf0_,wfh[1][0],G1); G1=mfma16(hf1_,wfh[1][1],G1); \
  G1=mfma16(hf2_,wfh[1][2],G1); G1=mfma16(hf3_,wfh[1][3],G1); \
  AN=mfma16(hf0_,wfh[2][0],AN); AN=mfma16(hf1_,wfh[2][1],AN); \
  AN=mfma16(hf2_,wfh[2][2],AN); AN=mfma16(hf3_,wfh[2][3],AN); }

// rr = sigmoid(pre_r) = rcp(1+exp2(G0)); nn = tanh = 1-2*rcp(1+exp2(2L*x));
// hv = nn + zz*(hp-nn)  [fma form]
#define GATES(G0,G1,G2,AN) { int nxt_=cur^1; \
  _Pragma("unroll") \
  for (int r=0;r<4;++r){ \
    float rr_=frcp(1.0f+fexp2(G0[r])); \
    float zz_=frcp(1.0f+fexp2(G1[r])); \
    float nn_=1.0f-2.0f*frcp(1.0f+fexp2(G2[r]+rr_*AN[r])); \
    float hv_=nn_+zz_*(hp[r]-nn_); hp[r]=hv_; \
    HL(nxt_,lq*4+r,w*16+lr)=f2bf(hv_); } \
  BARRIER(); cur=nxt_; }

#define STEPB(G0,G1,G2,SN,tt) { \
  GH(G0,G1,ANr); \
  GATES(G0,G1,G2,ANr); \
  if ((tt)+2 < T){ GIMM(G0,G1,G2,SN); } \
  ALOAD(SN,(tt)+4); }

static __device__ void gru_run(int mode, int s, int g, const P& p, u16* hl){
  const u16* A; size_t rstride; int T, oMode; u16* ho;
  const u16 *Wi, *Wh; const float *biP, *bhP;
  if (mode == 0){
    T = 32; oMode = 0;
    if (s < 2){ A = p.mon_xT + (size_t)s*24576*128; rstride = 768*128; }
    else      { A = p.vis_org + (size_t)(s-2)*768*128; rstride = 0; }
    Wi = p.mWih_b + (size_t)s*49152; Wh = p.mWhh_b + (size_t)s*49152;
    biP = p.mbih + (size_t)s*384;  bhP = p.mbhh + (size_t)s*384;
    int slot = (0x32140u >> (4*s)) & 15;
    ho = p.hin2T + (size_t)slot*768*128;
  } else {
    T = 16; oMode = 1;
    A = p.hin2T + (size_t)s*768*128; rstride = 48*128;
    int vi = (0x6514320u >> (4*s)) & 15;
    Wi = p.vWih_b + (size_t)vi*49152; Wh = p.vWhh_b + (size_t)vi*49152;
    biP = p.vbih + (size_t)vi*384;  bhP = p.vbhh + (size_t)vi*384;
    ho = p.h2 + (size_t)s*48*128;
  }
  int w = threadIdx.x >> 6, l = threadIdx.x & 63;
  int lr = l & 15, lq = l >> 4;

  bf8 wfi[3][4], wfh[3][4];
  #pragma unroll
  for (int j = 0; j < 3; ++j){
    int colb = (w + 8*j)*16;
    const u16* wpi = Wi + (size_t)(colb + lr)*128 + lq*8;
    const u16* wph = Wh + (size_t)(colb + lr)*128 + lq*8;
    #pragma unroll
    for (int kt = 0; kt < 4; ++kt){
      wfi[j][kt] = *(const bf8*)(wpi + kt*32);
      wfh[j][kt] = *(const bf8*)(wph + kt*32);
    }
  }
  float bs0_ = -LOG2E*(biP[w*16 + lr]     + bhP[w*16 + lr]);
  float bs1_ = -LOG2E*(biP[(8+w)*16 + lr] + bhP[(8+w)*16 + lr]);
  float bin_ =  TWOL*biP[(16+w)*16 + lr];
  float bhn_ =  TWOL*bhP[(16+w)*16 + lr];

  const u16* ap = A + (size_t)(g*16 + lr)*128 + lq*8;
  float hp[4] = {0.f,0.f,0.f,0.f};
  int cur = 0;
  f4 ANr;

  if (rstride){
    bf8 S0[4], S1[4];
    f4 gE0,gE1,gE2, gO0,gO1,gO2;
    ALOAD(S0,0); ALOAD(S1,1);
    GIMM(gE0,gE1,gE2,S0); ALOAD(S0,2);
    GIMM(gO0,gO1,gO2,S1); ALOAD(S1,3);
    { f4 an0={bhn_,bhn_,bhn_,bhn_}; ANr=an0;
      GATES(gE0,gE1,gE2,ANr); }               // t=0 (h0=0)
    GIMM(gE0,gE1,gE2,S0); ALOAD(S0,4);
    STEPB(gO0,gO1,gO2,S1,1);
    for (int t = 2; t < T; t += 2){
      STEPB(gE0,gE1,gE2,S0,t);
      STEPB(gO0,gO1,gO2,S1,t+1);
    }
  } else {
    f4 C0,C1,C2;
    { bf8 S0[4]; ALOAD(S0,0); GIMM(C0,C1,C2,S0); }   // constant gi
    { f4 an0={bhn_,bhn_,bhn_,bhn_}; ANr=an0;
      GATES(C0,C1,C2,ANr); }                  // t=0
    for (int t = 1; t < T; ++t){
      f4 G0=C0, G1=C1;
      GH(G0,G1,ANr);
      GATES(G0,G1,C2,ANr);
    }
  }

  if (oMode == 0){
    #pragma unroll
    for (int r = 0; r < 4; ++r)
      ho[((size_t)(lq*4+r)*48 + g)*128 + w*16 + lr] = f2bf(hp[r]);
  } else {
    #pragma unroll
    for (int r = 0; r < 4; ++r)
      ho[((size_t)(g*16 + lq*4 + r))*128 + w*16 + lr] = f2bf(hp[r]);
  }
}

// ---------------- the cooperative mega-kernel ----------------
__global__ __launch_bounds__(512, 2) void k_all(P p){
  cg::grid_group grid = cg::this_grid();
  int bid = blockIdx.x, tid = threadIdx.x;
  __shared__ __align__(16) u16 hl[4224];     // 2*16*132 (GRU h ping-pong)
  __shared__ int ids_s[256];
  __shared__ float emb2[2][896];

  // ---- A1: f32->bf16 conversions (GRU weights gate-scaled; emb tables plain) ----
  {
    int gi = bid*512 + tid;
    for (int i = gi; i < 614912; i += 131072){
      const float* s; u16* d; int off; bool scaled = false;
      if      (i < 61440)  { s=p.mWih_f; d=p.mWih_b; off=i;        scaled=true; }
      else if (i < 122880) { s=p.mWhh_f; d=p.mWhh_b; off=i-61440;  scaled=true; }
      else if (i < 208896) { s=p.vWih_f; d=p.vWih_b; off=i-122880; scaled=true; }
      else if (i < 294912) { s=p.vWhh_f; d=p.vWhh_b; off=i-208896; scaled=true; }
      else if (i < 422912) { s=p.embm;   d=p.embm_b; off=i-294912; }
      else                 { s=p.embv;   d=p.embv_b; off=i-422912; }
      float sc = 1.0f;
      if (scaled){ int row = (off >> 5) % 384; sc = (row < 256) ? -LOG2E : TWOL; }
      float4 v = *(const float4*)(s + (size_t)off*4);
      ushort4 o = { f2bf(v.x*sc), f2bf(v.y*sc), f2bf(v.z*sc), f2bf(v.w*sc) };
      *(ushort4*)(d + (size_t)off*4) = o;
    }
  }
  grid.sync();

  // ---- A2: bags (bf16 gathers) + weight/age linears ----
  {
    // monitor bags: 3072 tasks x 16 rows (uniform 12 iters)
    for (int it = 0; it < 12; ++it){
      int task = bid + it*256;
      int pp = task / 1536, trow0 = (task - pp*1536) * 16;
      if (tid < 256){
        int rr = tid >> 4, c = tid & 15;
        int f = 2*pp + (c >> 3), cm = c & 7;
        ids_s[tid] = p.mids[((size_t)f*24576 + trow0 + rr)*8 + cm];
      }
      __syncthreads();
      int rid = tid >> 5, lane = tid & 31, d0 = lane*4;
      const u16* e1 = p.embm_b + (size_t)(2*pp)*128000;
      const u16* e2 = p.embm_b + (size_t)(2*pp+1)*128000;
      float a0=0.f,a1=0.f,a2=0.f,a3=0.f;
      #pragma unroll
      for (int c = 0; c < 8; ++c){
        int i1 = ids_s[rid*16 + c], i2 = ids_s[rid*16 + 8 + c];
        if (i1 && i2){
          uint2 a = *(const uint2*)(e1 + (size_t)i1*128 + d0);
          uint2 b = *(const uint2*)(e2 + (size_t)i2*128 + d0);
          a0 += bflo(a.x)*bflo(b.x); a1 += bfhi(a.x)*bfhi(b.x);
          a2 += bflo(a.y)*bflo(b.y); a3 += bfhi(a.y)*bfhi(b.y);
        }
      }
      size_t nm = (size_t)trow0 + rid;
      int bv = (int)(nm >> 5), m = (int)(nm & 31);
      ushort4 o = { f2bf(a0), f2bf(a1), f2bf(a2), f2bf(a3) };
      *(ushort4*)(p.mon_xT + (size_t)pp*24576*128 + ((size_t)m*768 + bv)*128 + d0) = o;
      __syncthreads();
    }
    // visit bags: 576 tasks x 4 rows (guarded 3 iters)
    for (int it = 0; it < 3; ++it){
      int task = bid + it*256;
      bool act = task < 576;
      if (act && tid < 192){
        int rr = tid / 48, c = tid - rr*48;
        int row = task*4 + rr;
        int k = row / 768, bv = row - k*768;
        ids_s[tid] = p.vids[((size_t)k*768 + bv)*48 + c];
      }
      __syncthreads();
      if (act){
        int sub = tid >> 7, d = tid & 127;
        int row = task*4 + sub;
        int k = row / 768, bv = row - k*768;
        const u16* eb = p.embv_b + (size_t)k*256000;
        float acc = 0.f;
        #pragma unroll 4
        for (int c = 0; c < 48; ++c){
          int id = ids_s[sub*48 + c];
          if (id) acc += bf2f(eb[(size_t)id*128 + d]);
        }
        p.vis_org[((size_t)k*768 + bv)*128 + d] = f2bf(acc);
      }
      __syncthreads();
    }
    // weight/age linears: 384 tasks x 4 rows (no shared; plain stride)
    for (int task = bid; task < 384; task += 256){
      int sub = tid >> 7, d = tid & 127;
      int grow = task*4 + sub;
      int sidx = grow >= 768 ? 1 : 0;
      int row = grow - sidx*768;
      const float* vals = sidx ? p.av : p.wv;
      const float* wgt  = sidx ? p.aw : p.ww;
      const float* bias = sidx ? p.ab : p.wb;
      float v = vals[row];
      float h = (v != 0.f) ? (v * wgt[d] + bias[d]) : 0.f;
      int b = row >> 4, vv = row & 15;
      p.hin2T[((size_t)(5+sidx)*768 + (size_t)vv*48 + b)*128 + d] = f2bf(h);
    }
  }
  grid.sync();

  // ---- B: monitor-level GRU, streams 0..4 (240 blocks, all co-resident) ----
  if (bid < 240) gru_run(0, bid/48, bid%48, p, hl);
  grid.sync();

  // ---- C: visit-level GRU, streams 0..6 (21 blocks) ----
  if (bid < 21) gru_run(1, bid/3, bid%3, p, hl);
  grid.sync();

  // ---- D: final projection (24 blocks x 2 rows) ----
  if (bid < 24){
    int sub = tid >> 8, t = tid & 255;
    int b = bid*2 + sub;
    for (int i = t; i < 896; i += 256){
      int j = i >> 7, d = i & 127;
      float v = bf2f(p.h2[((size_t)j*48 + b)*128 + d]);
      if (j >= 1 && j <= 3) v *= 2.0f;   // slots 1..3 appear twice in reference
      emb2[sub][i] = fmaxf(v, 0.f);
    }
    __syncthreads();
    float acc = p.fcb[t];
    const float* wp = p.fcw + (size_t)t*896;
    float* outp = p.out + (size_t)b*256 + t;
    float s0 = 0.f;
    for (int i = 0; i < 896; i += 8){
      float4 w0 = *(const float4*)(wp + i);
      float4 w1 = *(const float4*)(wp + i + 4);
      s0 += w0.x*emb2[sub][i]   + w0.y*emb2[sub][i+1] + w0.z*emb2[sub][i+2] + w0.w*emb2[sub][i+3];
      s0 += w1.x*emb2[sub][i+4] + w1.y*emb2[sub][i+5] + w1.z*emb2[sub][i+6] + w1.w*emb2[sub][i+7];
    }
    *outp = acc + s0;
  }
}

extern "C" void kernel_launch(void* const* d_in, const int* in_sizes, int n_in,
                              void* d_out, int out_size, void* d_ws, size_t ws_size,
                              hipStream_t stream){
  P prm;
  prm.vids   = (const int*)d_in[0];
  prm.mids   = (const int*)d_in[1];
  prm.wv     = (const float*)d_in[2];
  prm.av     = (const float*)d_in[3];
  prm.embv   = (const float*)d_in[4];
  prm.embm   = (const float*)d_in[5];
  prm.mWih_f = (const float*)d_in[6];
  prm.mWhh_f = (const float*)d_in[7];
  prm.mbih   = (const float*)d_in[8];
  prm.mbhh   = (const float*)d_in[9];
  prm.vWih_f = (const float*)d_in[10];
  prm.vWhh_f = (const float*)d_in[11];
  prm.vbih   = (const float*)d_in[12];
  prm.vbhh   = (const float*)d_in[13];
  prm.ww     = (const float*)d_in[14];
  prm.wb     = (const float*)d_in[15];
  prm.aw     = (const float*)d_in[16];
  prm.ab     = (const float*)d_in[17];
  prm.fcw    = (const float*)d_in[18];
  prm.fcb    = (const float*)d_in[19];
  prm.out    = (float*)d_out;

  char* ws = (char*)d_ws;
  size_t o = 0;
  prm.mWih_b = (u16*)(ws+o); o += 5ull*384*128*2;
  prm.mWhh_b = (u16*)(ws+o); o += 5ull*384*128*2;
  prm.vWih_b = (u16*)(ws+o); o += 7ull*384*128*2;
  prm.vWhh_b = (u16*)(ws+o); o += 7ull*384*128*2;
  prm.embm_b = (u16*)(ws+o); o += 4ull*1000*128*2;
  prm.embv_b = (u16*)(ws+o); o += 3ull*2000*128*2;
  prm.mon_xT = (u16*)(ws+o); o += 2ull*24576*128*2;   // [p][m*768+bv][128]
  prm.vis_org= (u16*)(ws+o); o += 3ull*768*128*2;
  prm.hin2T  = (u16*)(ws+o); o += 7ull*768*128*2;     // [slot][v*48+b][128]
  prm.h2     = (u16*)(ws+o); o += 7ull*48*128*2;      // ~19.5 MB total

  void* args[] = { &prm };
  hipLaunchCooperativeKernel((void*)k_all, dim3(256), dim3(512), args, 0, stream);
}

// Round 13
// 124.766 us; speedup vs baseline: 2.5774x; 2.5774x over previous
//
#include <hip/hip_runtime.h>
#include <stdint.h>

// PersonalMed on MI355X. B=48,V=16,M=32,C=48,CM=8,D=128,OUT=256. f32 in/out.
// Round-13: r11 structure (measured best, 125us) + r12's numerically-validated
// gate-scale folding (r/z weight rows x -log2e, n rows x 2log2e at conversion;
// 3 fewer muls/row/step in the serial gate chain; fma-form h update).
// Ledger: coop launch starves TLP (r12, 2.5x); fold>256 blocks serializes
// (r9/r10); >1 chain/wave ~2x step (r7/r8); pre-barrier work paid xT (r9);
// IEEE-div gates were the old 60us floor (r6).

typedef unsigned short u16;
typedef uint32_t u32;
typedef short bf8 __attribute__((ext_vector_type(8)));   // 8 bf16 = 4 VGPRs
typedef float f4 __attribute__((ext_vector_type(4)));

static __device__ __forceinline__ float bf2f(u16 b){ u32 u=((u32)b)<<16; float f; __builtin_memcpy(&f,&u,4); return f; }
static __device__ __forceinline__ u16 f2bf(float f){ u32 u; __builtin_memcpy(&u,&f,4); u32 r=(u+0x7fffu+((u>>16)&1u))>>16; return (u16)r; }
static __device__ __forceinline__ f4 mfma16(bf8 a, bf8 b, f4 c){ return __builtin_amdgcn_mfma_f32_16x16x32_bf16(a,b,c,0,0,0); }

#if __has_builtin(__builtin_amdgcn_exp2f)
static __device__ __forceinline__ float fexp2(float x){ return __builtin_amdgcn_exp2f(x); }
#else
static __device__ __forceinline__ float fexp2(float x){ float r; asm volatile("v_exp_f32 %0, %1" : "=v"(r) : "v"(x)); return r; }
#endif
#if __has_builtin(__builtin_amdgcn_rcpf)
static __device__ __forceinline__ float frcp(float x){ return __builtin_amdgcn_rcpf(x); }
#else
static __device__ __forceinline__ float frcp(float x){ float r; asm volatile("v_rcp_f32 %0, %1" : "=v"(r) : "v"(x)); return r; }
#endif
#define LOG2E 1.44269504089f
#define TWOL  2.88539008178f

// ============ k_bags: ALL front-end work in one dispatch, grid (3072,3) block 256 ============
// y=0/1 : monitor bag p=y from f32 tables, 8 rows/block.
// y=2   : x<1152: visit bags from f32 (2 rows/block of 2304)
//         1152<=x<1920: weight/age linears (2 rows/block of 1536)
//         1920<=x<3072: GRU weights f32->bf16 with GATE SCALES folded
//         (row<256 i.e. r/z: x-log2e ; row>=256 i.e. n: x2log2e)
__global__ __launch_bounds__(256) void k_bags(const int* __restrict__ vids, const int* __restrict__ mids,
    const float* __restrict__ embv, const float* __restrict__ embm,
    const float* __restrict__ wv, const float* __restrict__ av,
    const float* __restrict__ ww, const float* __restrict__ wb,
    const float* __restrict__ aw, const float* __restrict__ ab,
    const float* __restrict__ mWih_f, const float* __restrict__ mWhh_f,
    const float* __restrict__ vWih_f, const float* __restrict__ vWhh_f,
    u16* __restrict__ mWih_b, u16* __restrict__ mWhh_b,
    u16* __restrict__ vWih_b, u16* __restrict__ vWhh_b,
    u16* __restrict__ mon_xT, u16* __restrict__ vis_org, u16* __restrict__ hin2T){
  int y = blockIdx.y;
  if (y < 2){
    int p = y;
    int rid = threadIdx.x >> 5, lane32 = threadIdx.x & 31, d0 = lane32*4;
    __shared__ int ids[8][16];
    if (threadIdx.x < 128){
      int rr = threadIdx.x >> 4, c = threadIdx.x & 15;
      int f = 2*p + (c>>3), cm = c & 7;
      ids[rr][c] = mids[((size_t)f*24576 + (size_t)blockIdx.x*8 + rr)*8 + cm];
    }
    __syncthreads();
    const float* e1 = embm + (size_t)(2*p)*1000*128;
    const float* e2 = embm + (size_t)(2*p+1)*1000*128;
    float a0=0.f,a1=0.f,a2=0.f,a3=0.f;
    #pragma unroll
    for (int c = 0; c < 8; ++c){
      int i1 = ids[rid][c], i2 = ids[rid][8+c];
      if (i1 && i2){
        float4 a = *(const float4*)(e1 + (size_t)i1*128 + d0);
        float4 b = *(const float4*)(e2 + (size_t)i2*128 + d0);
        a0 += a.x*b.x; a1 += a.y*b.y; a2 += a.z*b.z; a3 += a.w*b.w;
      }
    }
    size_t nm = (size_t)blockIdx.x*8 + rid;
    int bv = (int)(nm >> 5), m = (int)(nm & 31);
    ushort4 o = { f2bf(a0), f2bf(a1), f2bf(a2), f2bf(a3) };
    *(ushort4*)(mon_xT + (size_t)p*24576*128 + ((size_t)m*768 + bv)*128 + d0) = o;
  } else {
    int x = blockIdx.x;
    if (x < 1152){                                  // visit bags
      __shared__ int ids[2][48];
      int sub = threadIdx.x >> 7, d = threadIdx.x & 127;
      int row = x*2 + sub;
      int k = row / 768, bv = row - k*768;
      if (d < 48) ids[sub][d] = vids[((size_t)k*768 + bv)*48 + d];
      __syncthreads();
      const float* eb = embv + (size_t)k*2000*128;
      float acc = 0.f;
      #pragma unroll 4
      for (int c = 0; c < 48; ++c){ int id = ids[sub][c]; if (id) acc += eb[(size_t)id*128 + d]; }
      vis_org[((size_t)k*768 + bv)*128 + d] = f2bf(acc);
    } else if (x < 1920){                           // weight/age linears
      int sub = threadIdx.x >> 7, d = threadIdx.x & 127;
      int grow = (x - 1152)*2 + sub;
      int sidx = grow >= 768 ? 1 : 0;
      int row = grow - sidx*768;
      const float* vals = sidx ? av : wv;
      const float* wgt  = sidx ? aw : ww;
      const float* bias = sidx ? ab : wb;
      float v = vals[row];
      float h = (v != 0.f) ? (v * wgt[d] + bias[d]) : 0.f;
      int b = row >> 4, vv = row & 15;
      hin2T[((size_t)(5+sidx)*768 + (size_t)vv*48 + b)*128 + d] = f2bf(h);
    } else {                                        // GRU weight conversion (gate-scaled)
      int i = (x - 1920)*256 + threadIdx.x;         // float4 index < 294912
      const float* s; u16* d; int off;
      if      (i < 61440)  { s=mWih_f; d=mWih_b; off=i; }
      else if (i < 122880) { s=mWhh_f; d=mWhh_b; off=i-61440; }
      else if (i < 208896) { s=vWih_f; d=vWih_b; off=i-122880; }
      else                 { s=vWhh_f; d=vWhh_b; off=i-208896; }
      int row = (off >> 5) % 384;                   // within-matrix output row
      float sc = (row < 256) ? -LOG2E : TWOL;
      float4 v = *(const float4*)(s + (size_t)off*4);
      ushort4 o = { f2bf(v.x*sc), f2bf(v.y*sc), f2bf(v.z*sc), f2bf(v.w*sc) };
      *(ushort4*)(d + (size_t)off*4) = o;
    }
  }
}

// ================= fused GRU (r6/r11 schedule + GH-merge + folded gate scales) =================
// phase 0: grid (48,5). s<2: T=32, A=mon_xT[s] (rstride=768*128); s=2..4:
//   T=32, A=vis_org[s-2] (rstride=0, const gi). mgru[s], out hin2T[slot 0x32140].
// phase 1: grid (3,7). T=16, A=hin2T[s] (rstride=48*128), vgru[0x6514320 nibble],
//   out h2[s].

#define BARRIER() asm volatile("s_waitcnt lgkmcnt(0)\n\ts_barrier" ::: "memory")

#define ALOAD(S, tt) { int t_=(tt); if (t_>=T) t_=0; \
  const u16* p_ = ap + (size_t)t_*rstride; \
  S[0]=*(const bf8*)(p_); S[1]=*(const bf8*)(p_+32); \
  S[2]=*(const bf8*)(p_+64); S[3]=*(const bf8*)(p_+96); }

// weights pre-scaled: G0/G1 = -L*pre_rz (accumulating), G2 = 2L*gi_n + bias
#define GIMM(G0,G1,G2,S) { \
  f4 t0_={bs0_,bs0_,bs0_,bs0_}; G0=t0_; \
  f4 t1_={bs1_,bs1_,bs1_,bs1_}; G1=t1_; \
  f4 t2_={bin_,bin_,bin_,bin_}; G2=t2_; \
  G0=mfma16(S[0],wfi[0][0],G0); G0=mfma16(S[1],wfi[0][1],G0); \
  G0=mfma16(S[2],wfi[0][2],G0); G0=mfma16(S[3],wfi[0][3],G0); \
  G1=mfma16(S[0],wfi[1][0],G1); G1=mfma16(S[1],wfi[1][1],G1); \
  G1=mfma16(S[2],wfi[1][2],G1); G1=mfma16(S[3],wfi[1][3],G1); \
  G2=mfma16(S[0],wfi[2][0],G2); G2=mfma16(S[1],wfi[2][1],G2); \
  G2=mfma16(S[2],wfi[2][2],G2); G2=mfma16(S[3],wfi[2][3],G2); }

// h@Whh chained into G0,G1 (C-operand); AN = 2L*bh_n + h@(2L*Whn). Reads hlds[cur].
#define GH(G0,G1,AN) { \
  bf8 hf0_=*(const bf8*)&hlds[cur][lr][lq*8]; \
  bf8 hf1_=*(const bf8*)&hlds[cur][lr][32+lq*8]; \
  bf8 hf2_=*(const bf8*)&hlds[cur][lr][64+lq*8]; \
  bf8 hf3_=*(const bf8*)&hlds[cur][lr][96+lq*8]; \
  f4 an_={bhn_,bhn_,bhn_,bhn_}; AN=an_; \
  G0=mfma16(hf0_,wfh[0][0],G0); G0=mfma16(hf1_,wfh[0][1],G0); \
  G0=mfma16(hf2_,wfh[0][2],G0); G0=mfma16(hf3_,wfh[0][3],G0); \
  G1=mfma16(hf0_,wfh[1][0],G1); G1=mfma16(hf1_,wfh[1][1],G1); \
  G1=mfma16(hf2_,wfh[1][2],G1); G1=mfma16(hf3_,wfh[1][3],G1); \
  AN=mfma16(hf0_,wfh[2][0],AN); AN=mfma16(hf1_,wfh[2][1],AN); \
  AN=mfma16(hf2_,wfh[2][2],AN); AN=mfma16(hf3_,wfh[2][3],AN); }

// rr = rcp(1+exp2(G0)) [= sigmoid, scale folded]; nn = 1-2*rcp(1+exp2(G2+rr*AN));
// hv = nn + zz*(hp-nn). ds_write; raw barrier; flip cur.
#define GATES(G0,G1,G2,AN) { int nxt_=cur^1; \
  _Pragma("unroll") \
  for (int r=0;r<4;++r){ \
    float rr_=frcp(1.0f+fexp2(G0[r])); \
    float zz_=frcp(1.0f+fexp2(G1[r])); \
    float nn_=1.0f-2.0f*frcp(1.0f+fexp2(G2[r]+rr_*AN[r])); \
    float hv_=nn_+zz_*(hp[r]-nn_); hp[r]=hv_; \
    hlds[nxt_][lq*4+r][w*16+lr]=f2bf(hv_); } \
  BARRIER(); cur=nxt_; }

// r6 schedule: GH -> GATES(+barrier) -> GIMM rebuild -> ALOAD refill.
#define STEPB(G0,G1,G2,SN,tt) { \
  GH(G0,G1,ANr); \
  GATES(G0,G1,G2,ANr); \
  if ((tt)+2 < T){ GIMM(G0,G1,G2,SN); } \
  ALOAD(SN,(tt)+4); }

__global__ __launch_bounds__(512, 2) void k_gru(int phase,
    const u16* __restrict__ mon_xT, const u16* __restrict__ vis_org,
    u16* __restrict__ hin2T, u16* __restrict__ h2,
    const u16* __restrict__ mWih, const float* __restrict__ mbih,
    const u16* __restrict__ mWhh, const float* __restrict__ mbhh,
    const u16* __restrict__ vWih, const float* __restrict__ vbih,
    const u16* __restrict__ vWhh, const float* __restrict__ vbhh){
  int s = blockIdx.y, g = blockIdx.x;
  const u16* A; size_t rstride; int T, oMode; u16* ho;
  const u16 *Wi, *Wh; const float *biP, *bhP;
  if (phase == 0){
    T = 32; oMode = 0;
    if (s < 2){ A = mon_xT + (size_t)s*24576*128; rstride = 768*128; }
    else      { A = vis_org + (size_t)(s-2)*768*128; rstride = 0; }
    Wi = mWih + (size_t)s*49152; Wh = mWhh + (size_t)s*49152;
    biP = mbih + (size_t)s*384;  bhP = mbhh + (size_t)s*384;
    int slot = (0x32140u >> (4*s)) & 15;
    ho = hin2T + (size_t)slot*768*128;
  } else {
    T = 16; oMode = 1;
    A = hin2T + (size_t)s*768*128; rstride = 48*128;
    int vi = (0x6514320u >> (4*s)) & 15;
    Wi = vWih + (size_t)vi*49152; Wh = vWhh + (size_t)vi*49152;
    biP = vbih + (size_t)vi*384;  bhP = vbhh + (size_t)vi*384;
    ho = h2 + (size_t)s*48*128;
  }

  int w = threadIdx.x >> 6, l = threadIdx.x & 63;
  int lr = l & 15, lq = l >> 4;

  // wave w owns gate-col-chunk w*16..+16 of r,z,n (tiles w, 8+w, 16+w)
  bf8 wfi[3][4], wfh[3][4];
  #pragma unroll
  for (int j = 0; j < 3; ++j){
    int colb = (w + 8*j)*16;
    const u16* wpi = Wi + (size_t)(colb + lr)*128 + lq*8;
    const u16* wph = Wh + (size_t)(colb + lr)*128 + lq*8;
    #pragma unroll
    for (int kt = 0; kt < 4; ++kt){
      wfi[j][kt] = *(const bf8*)(wpi + kt*32);
      wfh[j][kt] = *(const bf8*)(wph + kt*32);
    }
  }
  float bs0_ = -LOG2E*(biP[w*16 + lr]     + bhP[w*16 + lr]);    // r: -L*(bi+bh)
  float bs1_ = -LOG2E*(biP[(8+w)*16 + lr] + bhP[(8+w)*16 + lr]);// z: -L*(bi+bh)
  float bin_ =  TWOL*biP[(16+w)*16 + lr];                        // n: 2L*bi
  float bhn_ =  TWOL*bhP[(16+w)*16 + lr];                        // n: 2L*bh (in AN)

  const u16* ap = A + (size_t)(g*16 + lr)*128 + lq*8;
  __shared__ u16 hlds[2][16][132];   // 66-dword row stride: conflict-free b128
  float hp[4] = {0.f,0.f,0.f,0.f};
  int cur = 0;
  f4 ANr;

  if (rstride){
    bf8 S0[4], S1[4];
    f4 gE0,gE1,gE2, gO0,gO1,gO2;
    ALOAD(S0,0); ALOAD(S1,1);
    GIMM(gE0,gE1,gE2,S0); ALOAD(S0,2);      // gi(0); A(2) in flight
    GIMM(gO0,gO1,gO2,S1); ALOAD(S1,3);      // gi(1); A(3) in flight
    { // t=0: h0=0 -> gh contribution is just the (pre-scaled) biases
      f4 an0={bhn_,bhn_,bhn_,bhn_}; ANr=an0;
      GATES(gE0,gE1,gE2,ANr);
    }
    GIMM(gE0,gE1,gE2,S0); ALOAD(S0,4);      // gi(2); A(4) in flight
    STEPB(gO0,gO1,gO2,S1,1);                // t=1: consume gi(1), build gi(3)
    for (int t = 2; t < T; t += 2){
      STEPB(gE0,gE1,gE2,S0,t);
      STEPB(gO0,gO1,gO2,S1,t+1);
    }
  } else {
    f4 C0,C1,C2;
    {
      bf8 S0[4];
      ALOAD(S0,0);
      GIMM(C0,C1,C2,S0);                    // constant gi (+bias), computed once
    }
    { // t=0
      f4 an0={bhn_,bhn_,bhn_,bhn_}; ANr=an0;
      GATES(C0,C1,C2,ANr);
    }
    for (int t = 1; t < T; ++t){
      f4 G0=C0, G1=C1;
      GH(G0,G1,ANr);
      GATES(G0,G1,C2,ANr);
    }
  }

  if (oMode == 0){
    #pragma unroll
    for (int r = 0; r < 4; ++r)
      ho[((size_t)(lq*4+r)*48 + g)*128 + w*16 + lr] = f2bf(hp[r]);
  } else {
    #pragma unroll
    for (int r = 0; r < 4; ++r)
      ho[((size_t)(g*16 + lq*4 + r))*128 + w*16 + lr] = f2bf(hp[r]);
  }
}

// ================= final projection =================
__global__ __launch_bounds__(256) void k_final(const u16* __restrict__ h2,
                                               const float* __restrict__ W,
                                               const float* __restrict__ Bias,
                                               float* __restrict__ out){
  int b = blockIdx.x, t = threadIdx.x;
  __shared__ float emb[896];
  for (int i = t; i < 896; i += 256){
    int j = i >> 7, d = i & 127;
    float v = bf2f(h2[((size_t)j*48 + b)*128 + d]);
    if (j >= 1 && j <= 3) v *= 2.0f;   // slots 1..3 appear twice in reference sum
    emb[i] = fmaxf(v, 0.f);
  }
  __syncthreads();
  float acc = Bias[t];
  const float* wp = W + (size_t)t*896;
  for (int i = 0; i < 896; i += 8){
    float4 w0 = *(const float4*)(wp + i);
    float4 w1 = *(const float4*)(wp + i + 4);
    acc += w0.x*emb[i]   + w0.y*emb[i+1] + w0.z*emb[i+2] + w0.w*emb[i+3];
    acc += w1.x*emb[i+4] + w1.y*emb[i+5] + w1.z*emb[i+6] + w1.w*emb[i+7];
  }
  out[(size_t)b*256 + t] = acc;
}

extern "C" void kernel_launch(void* const* d_in, const int* in_sizes, int n_in,
                              void* d_out, int out_size, void* d_ws, size_t ws_size,
                              hipStream_t stream){
  const int*   visit_ids   = (const int*)d_in[0];
  const int*   mon_ids     = (const int*)d_in[1];
  const float* weight_vals = (const float*)d_in[2];
  const float* age_vals    = (const float*)d_in[3];
  const float* emb_visit   = (const float*)d_in[4];
  const float* emb_mon     = (const float*)d_in[5];
  const float* mgru_Wih    = (const float*)d_in[6];
  const float* mgru_Whh    = (const float*)d_in[7];
  const float* mgru_bih    = (const float*)d_in[8];
  const float* mgru_bhh    = (const float*)d_in[9];
  const float* vgru_Wih    = (const float*)d_in[10];
  const float* vgru_Whh    = (const float*)d_in[11];
  const float* vgru_bih    = (const float*)d_in[12];
  const float* vgru_bhh    = (const float*)d_in[13];
  const float* fc_w_w      = (const float*)d_in[14];
  const float* fc_w_b      = (const float*)d_in[15];
  const float* fc_a_w      = (const float*)d_in[16];
  const float* fc_a_b      = (const float*)d_in[17];
  const float* fc_out_w    = (const float*)d_in[18];
  const float* fc_out_b    = (const float*)d_in[19];

  char* ws = (char*)d_ws;
  size_t o = 0;
  u16* mWih_b  = (u16*)(ws+o); o += 5ull*384*128*2;
  u16* mWhh_b  = (u16*)(ws+o); o += 5ull*384*128*2;
  u16* vWih_b  = (u16*)(ws+o); o += 7ull*384*128*2;
  u16* vWhh_b  = (u16*)(ws+o); o += 7ull*384*128*2;
  u16* mon_xT  = (u16*)(ws+o); o += 2ull*24576*128*2;    // [p][m*768+bv][128]
  u16* vis_org = (u16*)(ws+o); o += 3ull*768*128*2;
  u16* hin2T   = (u16*)(ws+o); o += 7ull*768*128*2;      // [slot][v*48+b][128]
  u16* h2      = (u16*)(ws+o); o += 7ull*48*128*2;       // ~16.6 MB total

  // one front-end dispatch: bags + linears + gate-scaled weight conversion
  k_bags<<<dim3(3072,3), 256, 0, stream>>>(visit_ids, mon_ids, emb_visit, emb_mon,
      weight_vals, age_vals, fc_w_w, fc_w_b, fc_a_w, fc_a_b,
      mgru_Wih, mgru_Whh, vgru_Wih, vgru_Whh,
      mWih_b, mWhh_b, vWih_b, vWhh_b,
      mon_xT, vis_org, hin2T);
  // phase 0: monitor-level streams 0..4 (240 blocks <= 256 CUs)
  k_gru<<<dim3(48,5), 512, 0, stream>>>(0, mon_xT, vis_org, hin2T, h2,
      mWih_b, mgru_bih, mWhh_b, mgru_bhh, vWih_b, vgru_bih, vWhh_b, vgru_bhh);
  // phase 1: visit-level streams 0..6
  k_gru<<<dim3(3,7), 512, 0, stream>>>(1, mon_xT, vis_org, hin2T, h2,
      mWih_b, mgru_bih, mWhh_b, mgru_bhh, vWih_b, vgru_bih, vWhh_b, vgru_bhh);
  k_final<<<48, 256, 0, stream>>>(h2, fc_out_w, fc_out_b, (float*)d_out);
}

// Round 14
// 122.936 us; speedup vs baseline: 2.6158x; 1.0149x over previous
//
#include <hip/hip_runtime.h>
#include <stdint.h>

// PersonalMed on MI355X. B=48,V=16,M=32,C=48,CM=8,D=128,OUT=256. f32 in/out.
// Round-14: r13 GRU (best: ph0 42.6us, gate-scales folded) + request-rate-
// optimized front-end: bf16 tables via tiny k_prep, mon bag at 16B/lane
// (12.6M loads vs 25M), visit bag at 8B/lane (3.5M vs 14.2M scalar).
// Ledger: k_bags is LOAD-INSTRUCTION-bound not byte-bound (r9 bf16 ~= r11 f32);
// coop launch starves TLP (r12); fold>256 blocks serializes (r9/r10); >1
// chain/wave ~2x step (r7/r8); IEEE-div gates were the old 60us floor (r6).

typedef unsigned short u16;
typedef uint32_t u32;
typedef short bf8 __attribute__((ext_vector_type(8)));   // 8 bf16 = 4 VGPRs
typedef float f4 __attribute__((ext_vector_type(4)));

static __device__ __forceinline__ float bf2f(u16 b){ u32 u=((u32)b)<<16; float f; __builtin_memcpy(&f,&u,4); return f; }
static __device__ __forceinline__ u16 f2bf(float f){ u32 u; __builtin_memcpy(&u,&f,4); u32 r=(u+0x7fffu+((u>>16)&1u))>>16; return (u16)r; }
static __device__ __forceinline__ float bflo(u32 u){ u32 x=u<<16; float f; __builtin_memcpy(&f,&x,4); return f; }
static __device__ __forceinline__ float bfhi(u32 u){ u32 x=u&0xffff0000u; float f; __builtin_memcpy(&f,&x,4); return f; }
static __device__ __forceinline__ f4 mfma16(bf8 a, bf8 b, f4 c){ return __builtin_amdgcn_mfma_f32_16x16x32_bf16(a,b,c,0,0,0); }

#if __has_builtin(__builtin_amdgcn_exp2f)
static __device__ __forceinline__ float fexp2(float x){ return __builtin_amdgcn_exp2f(x); }
#else
static __device__ __forceinline__ float fexp2(float x){ float r; asm volatile("v_exp_f32 %0, %1" : "=v"(r) : "v"(x)); return r; }
#endif
#if __has_builtin(__builtin_amdgcn_rcpf)
static __device__ __forceinline__ float frcp(float x){ return __builtin_amdgcn_rcpf(x); }
#else
static __device__ __forceinline__ float frcp(float x){ float r; asm volatile("v_rcp_f32 %0, %1" : "=v"(r) : "v"(x)); return r; }
#endif
#define LOG2E 1.44269504089f
#define TWOL  2.88539008178f

// ===== k_prep: f32->bf16. GRU weights gate-scaled (r/z rows x -log2e, n x 2log2e);
// emb tables plain. float4 ranges: mWih 61440 | mWhh 61440 | vWih 86016 |
// vWhh 86016 | embm 128000 | embv 192000 => 614912 total, grid 2402x256.
__global__ __launch_bounds__(256) void k_prep(
    const float* __restrict__ s0, const float* __restrict__ s1,
    const float* __restrict__ s2, const float* __restrict__ s3,
    const float* __restrict__ s4, const float* __restrict__ s5,
    u16* __restrict__ d0, u16* __restrict__ d1, u16* __restrict__ d2,
    u16* __restrict__ d3, u16* __restrict__ d4, u16* __restrict__ d5){
  int i = blockIdx.x*256 + threadIdx.x;
  const float* s; u16* d; int off; bool scaled = true;
  if      (i < 61440)  { s=s0; d=d0; off=i; }
  else if (i < 122880) { s=s1; d=d1; off=i-61440; }
  else if (i < 208896) { s=s2; d=d2; off=i-122880; }
  else if (i < 294912) { s=s3; d=d3; off=i-208896; }
  else if (i < 422912) { s=s4; d=d4; off=i-294912; scaled=false; }
  else if (i < 614912) { s=s5; d=d5; off=i-422912; scaled=false; }
  else return;
  float sc = 1.0f;
  if (scaled){ int row = (off >> 5) % 384; sc = (row < 256) ? -LOG2E : TWOL; }
  float4 v = *(const float4*)(s + (size_t)off*4);
  ushort4 o = { f2bf(v.x*sc), f2bf(v.y*sc), f2bf(v.z*sc), f2bf(v.w*sc) };
  *(ushort4*)(d + (size_t)off*4) = o;
}

// ===== k_bags: wide-load bags + weight/age, grid (1536,3) block 256 =====
// y=0/1 : mon bag p=y, 16 rows/block, 16 lanes/row, 8 d/lane (uint4 16B loads)
// y=2   : x<288: visit bags, 8 rows/block, 32 lanes/row, 4 d/lane (uint2)
//         288<=x<672: weight/age linears (4 rows/block of 1536)
__global__ __launch_bounds__(256) void k_bags(const int* __restrict__ vids, const int* __restrict__ mids,
    const u16* __restrict__ embv_b, const u16* __restrict__ embm_b,
    const float* __restrict__ wv, const float* __restrict__ av,
    const float* __restrict__ ww, const float* __restrict__ wb,
    const float* __restrict__ aw, const float* __restrict__ ab,
    u16* __restrict__ mon_xT, u16* __restrict__ vis_org, u16* __restrict__ hin2T){
  int y = blockIdx.y;
  if (y < 2){
    int p = y;
    int rid = threadIdx.x >> 4, lane16 = threadIdx.x & 15, dd0 = lane16*8;
    __shared__ int ids[16][16];
    { // one id per thread: 16 rows x 16 (8 codes x 2 features)
      int rr = threadIdx.x >> 4, c = threadIdx.x & 15;
      int f = 2*p + (c >> 3), cm = c & 7;
      ids[rr][c] = mids[((size_t)f*24576 + (size_t)blockIdx.x*16 + rr)*8 + cm];
    }
    __syncthreads();
    const u16* e1 = embm_b + (size_t)(2*p)*1000*128;
    const u16* e2 = embm_b + (size_t)(2*p+1)*1000*128;
    float a0=0.f,a1=0.f,a2=0.f,a3=0.f,a4=0.f,a5=0.f,a6=0.f,a7=0.f;
    #pragma unroll
    for (int c = 0; c < 8; ++c){
      int i1 = ids[rid][c], i2 = ids[rid][8+c];
      if (i1 && i2){
        uint4 a = *(const uint4*)(e1 + (size_t)i1*128 + dd0);
        uint4 b = *(const uint4*)(e2 + (size_t)i2*128 + dd0);
        a0 += bflo(a.x)*bflo(b.x); a1 += bfhi(a.x)*bfhi(b.x);
        a2 += bflo(a.y)*bflo(b.y); a3 += bfhi(a.y)*bfhi(b.y);
        a4 += bflo(a.z)*bflo(b.z); a5 += bfhi(a.z)*bfhi(b.z);
        a6 += bflo(a.w)*bflo(b.w); a7 += bfhi(a.w)*bfhi(b.w);
      }
    }
    size_t nm = (size_t)blockIdx.x*16 + rid;
    int bv = (int)(nm >> 5), m = (int)(nm & 31);
    uint4 o;
    o.x = (u32)f2bf(a0) | ((u32)f2bf(a1) << 16);
    o.y = (u32)f2bf(a2) | ((u32)f2bf(a3) << 16);
    o.z = (u32)f2bf(a4) | ((u32)f2bf(a5) << 16);
    o.w = (u32)f2bf(a6) | ((u32)f2bf(a7) << 16);
    *(uint4*)(mon_xT + (size_t)p*24576*128 + ((size_t)m*768 + bv)*128 + dd0) = o;
  } else {
    int x = blockIdx.x;
    if (x < 288){                                   // visit bags: rows 8x..8x+7 of 2304
      __shared__ int ids[8][48];
      for (int i = threadIdx.x; i < 384; i += 256){
        int rr = i / 48, c = i - rr*48;
        int row = x*8 + rr;
        int k = row / 768, bv = row - k*768;
        ids[rr][c] = vids[((size_t)k*768 + bv)*48 + c];
      }
      __syncthreads();
      int rid = threadIdx.x >> 5, lane = threadIdx.x & 31, dd0 = lane*4;
      int row = x*8 + rid;
      int k = row / 768, bv = row - k*768;
      const u16* eb = embv_b + (size_t)k*2000*128;
      float a0=0.f,a1=0.f,a2=0.f,a3=0.f;
      #pragma unroll 4
      for (int c = 0; c < 48; ++c){
        int id = ids[rid][c];
        if (id){
          uint2 a = *(const uint2*)(eb + (size_t)id*128 + dd0);
          a0 += bflo(a.x); a1 += bfhi(a.x);
          a2 += bflo(a.y); a3 += bfhi(a.y);
        }
      }
      ushort4 o = { f2bf(a0), f2bf(a1), f2bf(a2), f2bf(a3) };
      *(ushort4*)(vis_org + ((size_t)k*768 + bv)*128 + dd0) = o;
    } else if (x < 672){                            // weight/age: 4 rows/block of 1536
      int sub = threadIdx.x >> 7, d = threadIdx.x & 127;
      for (int h2i = 0; h2i < 2; ++h2i){
        int grow = (x - 288)*4 + sub*2 + h2i;
        int sidx = grow >= 768 ? 1 : 0;
        int row = grow - sidx*768;
        const float* vals = sidx ? av : wv;
        const float* wgt  = sidx ? aw : ww;
        const float* bias = sidx ? ab : wb;
        float v = vals[row];
        float h = (v != 0.f) ? (v * wgt[d] + bias[d]) : 0.f;
        int b = row >> 4, vv = row & 15;
        hin2T[((size_t)(5+sidx)*768 + (size_t)vv*48 + b)*128 + d] = f2bf(h);
      }
    }
  }
}

// ================= fused GRU (r13: r6 schedule + GH-merge + folded gate scales) =================
// phase 0: grid (48,5). s<2: T=32, A=mon_xT[s] (rstride=768*128); s=2..4:
//   T=32, A=vis_org[s-2] (rstride=0, const gi). mgru[s], out hin2T[slot 0x32140].
// phase 1: grid (3,7). T=16, A=hin2T[s] (rstride=48*128), vgru[0x6514320 nibble],
//   out h2[s].

#define BARRIER() asm volatile("s_waitcnt lgkmcnt(0)\n\ts_barrier" ::: "memory")

#define ALOAD(S, tt) { int t_=(tt); if (t_>=T) t_=0; \
  const u16* p_ = ap + (size_t)t_*rstride; \
  S[0]=*(const bf8*)(p_); S[1]=*(const bf8*)(p_+32); \
  S[2]=*(const bf8*)(p_+64); S[3]=*(const bf8*)(p_+96); }

#define GIMM(G0,G1,G2,S) { \
  f4 t0_={bs0_,bs0_,bs0_,bs0_}; G0=t0_; \
  f4 t1_={bs1_,bs1_,bs1_,bs1_}; G1=t1_; \
  f4 t2_={bin_,bin_,bin_,bin_}; G2=t2_; \
  G0=mfma16(S[0],wfi[0][0],G0); G0=mfma16(S[1],wfi[0][1],G0); \
  G0=mfma16(S[2],wfi[0][2],G0); G0=mfma16(S[3],wfi[0][3],G0); \
  G1=mfma16(S[0],wfi[1][0],G1); G1=mfma16(S[1],wfi[1][1],G1); \
  G1=mfma16(S[2],wfi[1][2],G1); G1=mfma16(S[3],wfi[1][3],G1); \
  G2=mfma16(S[0],wfi[2][0],G2); G2=mfma16(S[1],wfi[2][1],G2); \
  G2=mfma16(S[2],wfi[2][2],G2); G2=mfma16(S[3],wfi[2][3],G2); }

#define GH(G0,G1,AN) { \
  bf8 hf0_=*(const bf8*)&hlds[cur][lr][lq*8]; \
  bf8 hf1_=*(const bf8*)&hlds[cur][lr][32+lq*8]; \
  bf8 hf2_=*(const bf8*)&hlds[cur][lr][64+lq*8]; \
  bf8 hf3_=*(const bf8*)&hlds[cur][lr][96+lq*8]; \
  f4 an_={bhn_,bhn_,bhn_,bhn_}; AN=an_; \
  G0=mfma16(hf0_,wfh[0][0],G0); G0=mfma16(hf1_,wfh[0][1],G0); \
  G0=mfma16(hf2_,wfh[0][2],G0); G0=mfma16(hf3_,wfh[0][3],G0); \
  G1=mfma16(hf0_,wfh[1][0],G1); G1=mfma16(hf1_,wfh[1][1],G1); \
  G1=mfma16(hf2_,wfh[1][2],G1); G1=mfma16(hf3_,wfh[1][3],G1); \
  AN=mfma16(hf0_,wfh[2][0],AN); AN=mfma16(hf1_,wfh[2][1],AN); \
  AN=mfma16(hf2_,wfh[2][2],AN); AN=mfma16(hf3_,wfh[2][3],AN); }

#define GATES(G0,G1,G2,AN) { int nxt_=cur^1; \
  _Pragma("unroll") \
  for (int r=0;r<4;++r){ \
    float rr_=frcp(1.0f+fexp2(G0[r])); \
    float zz_=frcp(1.0f+fexp2(G1[r])); \
    float nn_=1.0f-2.0f*frcp(1.0f+fexp2(G2[r]+rr_*AN[r])); \
    float hv_=nn_+zz_*(hp[r]-nn_); hp[r]=hv_; \
    hlds[nxt_][lq*4+r][w*16+lr]=f2bf(hv_); } \
  BARRIER(); cur=nxt_; }

#define STEPB(G0,G1,G2,SN,tt) { \
  GH(G0,G1,ANr); \
  GATES(G0,G1,G2,ANr); \
  if ((tt)+2 < T){ GIMM(G0,G1,G2,SN); } \
  ALOAD(SN,(tt)+4); }

__global__ __launch_bounds__(512, 2) void k_gru(int phase,
    const u16* __restrict__ mon_xT, const u16* __restrict__ vis_org,
    u16* __restrict__ hin2T, u16* __restrict__ h2,
    const u16* __restrict__ mWih, const float* __restrict__ mbih,
    const u16* __restrict__ mWhh, const float* __restrict__ mbhh,
    const u16* __restrict__ vWih, const float* __restrict__ vbih,
    const u16* __restrict__ vWhh, const float* __restrict__ vbhh){
  int s = blockIdx.y, g = blockIdx.x;
  const u16* A; size_t rstride; int T, oMode; u16* ho;
  const u16 *Wi, *Wh; const float *biP, *bhP;
  if (phase == 0){
    T = 32; oMode = 0;
    if (s < 2){ A = mon_xT + (size_t)s*24576*128; rstride = 768*128; }
    else      { A = vis_org + (size_t)(s-2)*768*128; rstride = 0; }
    Wi = mWih + (size_t)s*49152; Wh = mWhh + (size_t)s*49152;
    biP = mbih + (size_t)s*384;  bhP = mbhh + (size_t)s*384;
    int slot = (0x32140u >> (4*s)) & 15;
    ho = hin2T + (size_t)slot*768*128;
  } else {
    T = 16; oMode = 1;
    A = hin2T + (size_t)s*768*128; rstride = 48*128;
    int vi = (0x6514320u >> (4*s)) & 15;
    Wi = vWih + (size_t)vi*49152; Wh = vWhh + (size_t)vi*49152;
    biP = vbih + (size_t)vi*384;  bhP = vbhh + (size_t)vi*384;
    ho = h2 + (size_t)s*48*128;
  }

  int w = threadIdx.x >> 6, l = threadIdx.x & 63;
  int lr = l & 15, lq = l >> 4;

  bf8 wfi[3][4], wfh[3][4];
  #pragma unroll
  for (int j = 0; j < 3; ++j){
    int colb = (w + 8*j)*16;
    const u16* wpi = Wi + (size_t)(colb + lr)*128 + lq*8;
    const u16* wph = Wh + (size_t)(colb + lr)*128 + lq*8;
    #pragma unroll
    for (int kt = 0; kt < 4; ++kt){
      wfi[j][kt] = *(const bf8*)(wpi + kt*32);
      wfh[j][kt] = *(const bf8*)(wph + kt*32);
    }
  }
  float bs0_ = -LOG2E*(biP[w*16 + lr]     + bhP[w*16 + lr]);
  float bs1_ = -LOG2E*(biP[(8+w)*16 + lr] + bhP[(8+w)*16 + lr]);
  float bin_ =  TWOL*biP[(16+w)*16 + lr];
  float bhn_ =  TWOL*bhP[(16+w)*16 + lr];

  const u16* ap = A + (size_t)(g*16 + lr)*128 + lq*8;
  __shared__ u16 hlds[2][16][132];   // 66-dword row stride: conflict-free b128
  float hp[4] = {0.f,0.f,0.f,0.f};
  int cur = 0;
  f4 ANr;

  if (rstride){
    bf8 S0[4], S1[4];
    f4 gE0,gE1,gE2, gO0,gO1,gO2;
    ALOAD(S0,0); ALOAD(S1,1);
    GIMM(gE0,gE1,gE2,S0); ALOAD(S0,2);
    GIMM(gO0,gO1,gO2,S1); ALOAD(S1,3);
    { f4 an0={bhn_,bhn_,bhn_,bhn_}; ANr=an0;
      GATES(gE0,gE1,gE2,ANr); }               // t=0 (h0=0)
    GIMM(gE0,gE1,gE2,S0); ALOAD(S0,4);
    STEPB(gO0,gO1,gO2,S1,1);
    for (int t = 2; t < T; t += 2){
      STEPB(gE0,gE1,gE2,S0,t);
      STEPB(gO0,gO1,gO2,S1,t+1);
    }
  } else {
    f4 C0,C1,C2;
    { bf8 S0[4]; ALOAD(S0,0); GIMM(C0,C1,C2,S0); }   // constant gi
    { f4 an0={bhn_,bhn_,bhn_,bhn_}; ANr=an0;
      GATES(C0,C1,C2,ANr); }                  // t=0
    for (int t = 1; t < T; ++t){
      f4 G0=C0, G1=C1;
      GH(G0,G1,ANr);
      GATES(G0,G1,C2,ANr);
    }
  }

  if (oMode == 0){
    #pragma unroll
    for (int r = 0; r < 4; ++r)
      ho[((size_t)(lq*4+r)*48 + g)*128 + w*16 + lr] = f2bf(hp[r]);
  } else {
    #pragma unroll
    for (int r = 0; r < 4; ++r)
      ho[((size_t)(g*16 + lq*4 + r))*128 + w*16 + lr] = f2bf(hp[r]);
  }
}

// ================= final projection =================
__global__ __launch_bounds__(256) void k_final(const u16* __restrict__ h2,
                                               const float* __restrict__ W,
                                               const float* __restrict__ Bias,
                                               float* __restrict__ out){
  int b = blockIdx.x, t = threadIdx.x;
  __shared__ float emb[896];
  for (int i = t; i < 896; i += 256){
    int j = i >> 7, d = i & 127;
    float v = bf2f(h2[((size_t)j*48 + b)*128 + d]);
    if (j >= 1 && j <= 3) v *= 2.0f;   // slots 1..3 appear twice in reference sum
    emb[i] = fmaxf(v, 0.f);
  }
  __syncthreads();
  float acc = Bias[t];
  const float* wp = W + (size_t)t*896;
  for (int i = 0; i < 896; i += 8){
    float4 w0 = *(const float4*)(wp + i);
    float4 w1 = *(const float4*)(wp + i + 4);
    acc += w0.x*emb[i]   + w0.y*emb[i+1] + w0.z*emb[i+2] + w0.w*emb[i+3];
    acc += w1.x*emb[i+4] + w1.y*emb[i+5] + w1.z*emb[i+6] + w1.w*emb[i+7];
  }
  out[(size_t)b*256 + t] = acc;
}

extern "C" void kernel_launch(void* const* d_in, const int* in_sizes, int n_in,
                              void* d_out, int out_size, void* d_ws, size_t ws_size,
                              hipStream_t stream){
  const int*   visit_ids   = (const int*)d_in[0];
  const int*   mon_ids     = (const int*)d_in[1];
  const float* weight_vals = (const float*)d_in[2];
  const float* age_vals    = (const float*)d_in[3];
  const float* emb_visit   = (const float*)d_in[4];
  const float* emb_mon     = (const float*)d_in[5];
  const float* mgru_Wih    = (const float*)d_in[6];
  const float* mgru_Whh    = (const float*)d_in[7];
  const float* mgru_bih    = (const float*)d_in[8];
  const float* mgru_bhh    = (const float*)d_in[9];
  const float* vgru_Wih    = (const float*)d_in[10];
  const float* vgru_Whh    = (const float*)d_in[11];
  const float* vgru_bih    = (const float*)d_in[12];
  const float* vgru_bhh    = (const float*)d_in[13];
  const float* fc_w_w      = (const float*)d_in[14];
  const float* fc_w_b      = (const float*)d_in[15];
  const float* fc_a_w      = (const float*)d_in[16];
  const float* fc_a_b      = (const float*)d_in[17];
  const float* fc_out_w    = (const float*)d_in[18];
  const float* fc_out_b    = (const float*)d_in[19];

  char* ws = (char*)d_ws;
  size_t o = 0;
  u16* mWih_b  = (u16*)(ws+o); o += 5ull*384*128*2;
  u16* mWhh_b  = (u16*)(ws+o); o += 5ull*384*128*2;
  u16* vWih_b  = (u16*)(ws+o); o += 7ull*384*128*2;
  u16* vWhh_b  = (u16*)(ws+o); o += 7ull*384*128*2;
  u16* embm_b  = (u16*)(ws+o); o += 4ull*1000*128*2;
  u16* embv_b  = (u16*)(ws+o); o += 3ull*2000*128*2;
  u16* mon_xT  = (u16*)(ws+o); o += 2ull*24576*128*2;    // [p][m*768+bv][128]
  u16* vis_org = (u16*)(ws+o); o += 3ull*768*128*2;
  u16* hin2T   = (u16*)(ws+o); o += 7ull*768*128*2;      // [slot][v*48+b][128]
  u16* h2      = (u16*)(ws+o); o += 7ull*48*128*2;       // ~19 MB total

  k_prep<<<2402, 256, 0, stream>>>(mgru_Wih, mgru_Whh, vgru_Wih, vgru_Whh, emb_mon, emb_visit,
                                   mWih_b, mWhh_b, vWih_b, vWhh_b, embm_b, embv_b);
  k_bags<<<dim3(1536,3), 256, 0, stream>>>(visit_ids, mon_ids, embv_b, embm_b,
      weight_vals, age_vals, fc_w_w, fc_w_b, fc_a_w, fc_a_b,
      mon_xT, vis_org, hin2T);
  // phase 0: monitor-level streams 0..4 (240 blocks <= 256 CUs)
  k_gru<<<dim3(48,5), 512, 0, stream>>>(0, mon_xT, vis_org, hin2T, h2,
      mWih_b, mgru_bih, mWhh_b, mgru_bhh, vWih_b, vgru_bih, vWhh_b, vgru_bhh);
  // phase 1: visit-level streams 0..6
  k_gru<<<dim3(3,7), 512, 0, stream>>>(1, mon_xT, vis_org, hin2T, h2,
      mWih_b, mgru_bih, mWhh_b, mgru_bhh, vWih_b, vgru_bih, vWhh_b, vgru_bhh);
  k_final<<<48, 256, 0, stream>>>(h2, fc_out_w, fc_out_b, (float*)d_out);
}

// Round 15
// 122.790 us; speedup vs baseline: 2.6189x; 1.0012x over previous
//
#include <hip/hip_runtime.h>
#include <stdint.h>

// PersonalMed on MI355X. B=48,V=16,M=32,C=48,CM=8,D=128,OUT=256. f32 in/out.
// Round-15: r14 + depth-2 MFMA half-chains in GH (the serial-path MFMAs).
// G0/G1/AN each split into two 2-deep chains + vector add: 4L -> 2L+8 cyc
// on the 32x-repeated critical path. GIMM stays 4-deep (barrier-shadow work).
// Ledger: step latency ~3200cyc = 430 MFMA + 640 VALU + ~2100 exposed
// latency (barrier+ds+chains); k_bags is minor (r14); coop starves TLP (r12);
// fold>256 blocks serializes (r9/r10); >1 chain/wave ~2x step (r7/r8).

typedef unsigned short u16;
typedef uint32_t u32;
typedef short bf8 __attribute__((ext_vector_type(8)));   // 8 bf16 = 4 VGPRs
typedef float f4 __attribute__((ext_vector_type(4)));

static __device__ __forceinline__ float bf2f(u16 b){ u32 u=((u32)b)<<16; float f; __builtin_memcpy(&f,&u,4); return f; }
static __device__ __forceinline__ u16 f2bf(float f){ u32 u; __builtin_memcpy(&u,&f,4); u32 r=(u+0x7fffu+((u>>16)&1u))>>16; return (u16)r; }
static __device__ __forceinline__ float bflo(u32 u){ u32 x=u<<16; float f; __builtin_memcpy(&f,&x,4); return f; }
static __device__ __forceinline__ float bfhi(u32 u){ u32 x=u&0xffff0000u; float f; __builtin_memcpy(&f,&x,4); return f; }
static __device__ __forceinline__ f4 mfma16(bf8 a, bf8 b, f4 c){ return __builtin_amdgcn_mfma_f32_16x16x32_bf16(a,b,c,0,0,0); }

#if __has_builtin(__builtin_amdgcn_exp2f)
static __device__ __forceinline__ float fexp2(float x){ return __builtin_amdgcn_exp2f(x); }
#else
static __device__ __forceinline__ float fexp2(float x){ float r; asm volatile("v_exp_f32 %0, %1" : "=v"(r) : "v"(x)); return r; }
#endif
#if __has_builtin(__builtin_amdgcn_rcpf)
static __device__ __forceinline__ float frcp(float x){ return __builtin_amdgcn_rcpf(x); }
#else
static __device__ __forceinline__ float frcp(float x){ float r; asm volatile("v_rcp_f32 %0, %1" : "=v"(r) : "v"(x)); return r; }
#endif
#define LOG2E 1.44269504089f
#define TWOL  2.88539008178f

// ===== k_prep: f32->bf16. GRU weights gate-scaled (r/z rows x -log2e, n x 2log2e);
// emb tables plain. float4 ranges: mWih 61440 | mWhh 61440 | vWih 86016 |
// vWhh 86016 | embm 128000 | embv 192000 => 614912 total, grid 2402x256.
__global__ __launch_bounds__(256) void k_prep(
    const float* __restrict__ s0, const float* __restrict__ s1,
    const float* __restrict__ s2, const float* __restrict__ s3,
    const float* __restrict__ s4, const float* __restrict__ s5,
    u16* __restrict__ d0, u16* __restrict__ d1, u16* __restrict__ d2,
    u16* __restrict__ d3, u16* __restrict__ d4, u16* __restrict__ d5){
  int i = blockIdx.x*256 + threadIdx.x;
  const float* s; u16* d; int off; bool scaled = true;
  if      (i < 61440)  { s=s0; d=d0; off=i; }
  else if (i < 122880) { s=s1; d=d1; off=i-61440; }
  else if (i < 208896) { s=s2; d=d2; off=i-122880; }
  else if (i < 294912) { s=s3; d=d3; off=i-208896; }
  else if (i < 422912) { s=s4; d=d4; off=i-294912; scaled=false; }
  else if (i < 614912) { s=s5; d=d5; off=i-422912; scaled=false; }
  else return;
  float sc = 1.0f;
  if (scaled){ int row = (off >> 5) % 384; sc = (row < 256) ? -LOG2E : TWOL; }
  float4 v = *(const float4*)(s + (size_t)off*4);
  ushort4 o = { f2bf(v.x*sc), f2bf(v.y*sc), f2bf(v.z*sc), f2bf(v.w*sc) };
  *(ushort4*)(d + (size_t)off*4) = o;
}

// ===== k_bags: wide-load bags + weight/age, grid (1536,3) block 256 =====
// y=0/1 : mon bag p=y, 16 rows/block, 16 lanes/row, 8 d/lane (uint4 16B loads)
// y=2   : x<288: visit bags, 8 rows/block, 32 lanes/row, 4 d/lane (uint2)
//         288<=x<672: weight/age linears (4 rows/block of 1536)
__global__ __launch_bounds__(256) void k_bags(const int* __restrict__ vids, const int* __restrict__ mids,
    const u16* __restrict__ embv_b, const u16* __restrict__ embm_b,
    const float* __restrict__ wv, const float* __restrict__ av,
    const float* __restrict__ ww, const float* __restrict__ wb,
    const float* __restrict__ aw, const float* __restrict__ ab,
    u16* __restrict__ mon_xT, u16* __restrict__ vis_org, u16* __restrict__ hin2T){
  int y = blockIdx.y;
  if (y < 2){
    int p = y;
    int rid = threadIdx.x >> 4, lane16 = threadIdx.x & 15, dd0 = lane16*8;
    __shared__ int ids[16][16];
    {
      int rr = threadIdx.x >> 4, c = threadIdx.x & 15;
      int f = 2*p + (c >> 3), cm = c & 7;
      ids[rr][c] = mids[((size_t)f*24576 + (size_t)blockIdx.x*16 + rr)*8 + cm];
    }
    __syncthreads();
    const u16* e1 = embm_b + (size_t)(2*p)*1000*128;
    const u16* e2 = embm_b + (size_t)(2*p+1)*1000*128;
    float a0=0.f,a1=0.f,a2=0.f,a3=0.f,a4=0.f,a5=0.f,a6=0.f,a7=0.f;
    #pragma unroll
    for (int c = 0; c < 8; ++c){
      int i1 = ids[rid][c], i2 = ids[rid][8+c];
      if (i1 && i2){
        uint4 a = *(const uint4*)(e1 + (size_t)i1*128 + dd0);
        uint4 b = *(const uint4*)(e2 + (size_t)i2*128 + dd0);
        a0 += bflo(a.x)*bflo(b.x); a1 += bfhi(a.x)*bfhi(b.x);
        a2 += bflo(a.y)*bflo(b.y); a3 += bfhi(a.y)*bfhi(b.y);
        a4 += bflo(a.z)*bflo(b.z); a5 += bfhi(a.z)*bfhi(b.z);
        a6 += bflo(a.w)*bflo(b.w); a7 += bfhi(a.w)*bfhi(b.w);
      }
    }
    size_t nm = (size_t)blockIdx.x*16 + rid;
    int bv = (int)(nm >> 5), m = (int)(nm & 31);
    uint4 o;
    o.x = (u32)f2bf(a0) | ((u32)f2bf(a1) << 16);
    o.y = (u32)f2bf(a2) | ((u32)f2bf(a3) << 16);
    o.z = (u32)f2bf(a4) | ((u32)f2bf(a5) << 16);
    o.w = (u32)f2bf(a6) | ((u32)f2bf(a7) << 16);
    *(uint4*)(mon_xT + (size_t)p*24576*128 + ((size_t)m*768 + bv)*128 + dd0) = o;
  } else {
    int x = blockIdx.x;
    if (x < 288){                                   // visit bags: rows 8x..8x+7 of 2304
      __shared__ int ids[8][48];
      for (int i = threadIdx.x; i < 384; i += 256){
        int rr = i / 48, c = i - rr*48;
        int row = x*8 + rr;
        int k = row / 768, bv = row - k*768;
        ids[rr][c] = vids[((size_t)k*768 + bv)*48 + c];
      }
      __syncthreads();
      int rid = threadIdx.x >> 5, lane = threadIdx.x & 31, dd0 = lane*4;
      int row = x*8 + rid;
      int k = row / 768, bv = row - k*768;
      const u16* eb = embv_b + (size_t)k*2000*128;
      float a0=0.f,a1=0.f,a2=0.f,a3=0.f;
      #pragma unroll 4
      for (int c = 0; c < 48; ++c){
        int id = ids[rid][c];
        if (id){
          uint2 a = *(const uint2*)(eb + (size_t)id*128 + dd0);
          a0 += bflo(a.x); a1 += bfhi(a.x);
          a2 += bflo(a.y); a3 += bfhi(a.y);
        }
      }
      ushort4 o = { f2bf(a0), f2bf(a1), f2bf(a2), f2bf(a3) };
      *(ushort4*)(vis_org + ((size_t)k*768 + bv)*128 + dd0) = o;
    } else if (x < 672){                            // weight/age: 4 rows/block of 1536
      int sub = threadIdx.x >> 7, d = threadIdx.x & 127;
      for (int h2i = 0; h2i < 2; ++h2i){
        int grow = (x - 288)*4 + sub*2 + h2i;
        int sidx = grow >= 768 ? 1 : 0;
        int row = grow - sidx*768;
        const float* vals = sidx ? av : wv;
        const float* wgt  = sidx ? aw : ww;
        const float* bias = sidx ? ab : wb;
        float v = vals[row];
        float h = (v != 0.f) ? (v * wgt[d] + bias[d]) : 0.f;
        int b = row >> 4, vv = row & 15;
        hin2T[((size_t)(5+sidx)*768 + (size_t)vv*48 + b)*128 + d] = f2bf(h);
      }
    }
  }
}

// ================= fused GRU (r13 schedule + depth-2 GH half-chains) =================
// phase 0: grid (48,5). s<2: T=32, A=mon_xT[s] (rstride=768*128); s=2..4:
//   T=32, A=vis_org[s-2] (rstride=0, const gi). mgru[s], out hin2T[slot 0x32140].
// phase 1: grid (3,7). T=16, A=hin2T[s] (rstride=48*128), vgru[0x6514320 nibble],
//   out h2[s].

#define BARRIER() asm volatile("s_waitcnt lgkmcnt(0)\n\ts_barrier" ::: "memory")

#define ALOAD(S, tt) { int t_=(tt); if (t_>=T) t_=0; \
  const u16* p_ = ap + (size_t)t_*rstride; \
  S[0]=*(const bf8*)(p_); S[1]=*(const bf8*)(p_+32); \
  S[2]=*(const bf8*)(p_+64); S[3]=*(const bf8*)(p_+96); }

#define GIMM(G0,G1,G2,S) { \
  f4 t0_={bs0_,bs0_,bs0_,bs0_}; G0=t0_; \
  f4 t1_={bs1_,bs1_,bs1_,bs1_}; G1=t1_; \
  f4 t2_={bin_,bin_,bin_,bin_}; G2=t2_; \
  G0=mfma16(S[0],wfi[0][0],G0); G0=mfma16(S[1],wfi[0][1],G0); \
  G0=mfma16(S[2],wfi[0][2],G0); G0=mfma16(S[3],wfi[0][3],G0); \
  G1=mfma16(S[0],wfi[1][0],G1); G1=mfma16(S[1],wfi[1][1],G1); \
  G1=mfma16(S[2],wfi[1][2],G1); G1=mfma16(S[3],wfi[1][3],G1); \
  G2=mfma16(S[0],wfi[2][0],G2); G2=mfma16(S[1],wfi[2][1],G2); \
  G2=mfma16(S[2],wfi[2][2],G2); G2=mfma16(S[3],wfi[2][3],G2); }

// depth-2 half-chains: each gate = (2-deep chain on G) + (2-deep chain on temp) + add.
// Critical path 4L -> 2L + ~8cyc. Temps are transient (regalloc reuses).
#define GH(G0,G1,AN) { \
  bf8 hf0_=*(const bf8*)&hlds[cur][lr][lq*8]; \
  bf8 hf1_=*(const bf8*)&hlds[cur][lr][32+lq*8]; \
  bf8 hf2_=*(const bf8*)&hlds[cur][lr][64+lq*8]; \
  bf8 hf3_=*(const bf8*)&hlds[cur][lr][96+lq*8]; \
  f4 z_={0.f,0.f,0.f,0.f}; \
  f4 u0_=z_, u1_=z_, u2_=z_; \
  f4 an_={bhn_,bhn_,bhn_,bhn_}; AN=an_; \
  G0=mfma16(hf0_,wfh[0][0],G0); u0_=mfma16(hf2_,wfh[0][2],u0_); \
  G1=mfma16(hf0_,wfh[1][0],G1); u1_=mfma16(hf2_,wfh[1][2],u1_); \
  AN=mfma16(hf0_,wfh[2][0],AN); u2_=mfma16(hf2_,wfh[2][2],u2_); \
  G0=mfma16(hf1_,wfh[0][1],G0); u0_=mfma16(hf3_,wfh[0][3],u0_); \
  G1=mfma16(hf1_,wfh[1][1],G1); u1_=mfma16(hf3_,wfh[1][3],u1_); \
  AN=mfma16(hf1_,wfh[2][1],AN); u2_=mfma16(hf3_,wfh[2][3],u2_); \
  G0 = G0 + u0_; G1 = G1 + u1_; AN = AN + u2_; }

#define GATES(G0,G1,G2,AN) { int nxt_=cur^1; \
  _Pragma("unroll") \
  for (int r=0;r<4;++r){ \
    float rr_=frcp(1.0f+fexp2(G0[r])); \
    float zz_=frcp(1.0f+fexp2(G1[r])); \
    float nn_=1.0f-2.0f*frcp(1.0f+fexp2(G2[r]+rr_*AN[r])); \
    float hv_=nn_+zz_*(hp[r]-nn_); hp[r]=hv_; \
    hlds[nxt_][lq*4+r][w*16+lr]=f2bf(hv_); } \
  BARRIER(); cur=nxt_; }

#define STEPB(G0,G1,G2,SN,tt) { \
  GH(G0,G1,ANr); \
  GATES(G0,G1,G2,ANr); \
  if ((tt)+2 < T){ GIMM(G0,G1,G2,SN); } \
  ALOAD(SN,(tt)+4); }

__global__ __launch_bounds__(512, 2) void k_gru(int phase,
    const u16* __restrict__ mon_xT, const u16* __restrict__ vis_org,
    u16* __restrict__ hin2T, u16* __restrict__ h2,
    const u16* __restrict__ mWih, const float* __restrict__ mbih,
    const u16* __restrict__ mWhh, const float* __restrict__ mbhh,
    const u16* __restrict__ vWih, const float* __restrict__ vbih,
    const u16* __restrict__ vWhh, const float* __restrict__ vbhh){
  int s = blockIdx.y, g = blockIdx.x;
  const u16* A; size_t rstride; int T, oMode; u16* ho;
  const u16 *Wi, *Wh; const float *biP, *bhP;
  if (phase == 0){
    T = 32; oMode = 0;
    if (s < 2){ A = mon_xT + (size_t)s*24576*128; rstride = 768*128; }
    else      { A = vis_org + (size_t)(s-2)*768*128; rstride = 0; }
    Wi = mWih + (size_t)s*49152; Wh = mWhh + (size_t)s*49152;
    biP = mbih + (size_t)s*384;  bhP = mbhh + (size_t)s*384;
    int slot = (0x32140u >> (4*s)) & 15;
    ho = hin2T + (size_t)slot*768*128;
  } else {
    T = 16; oMode = 1;
    A = hin2T + (size_t)s*768*128; rstride = 48*128;
    int vi = (0x6514320u >> (4*s)) & 15;
    Wi = vWih + (size_t)vi*49152; Wh = vWhh + (size_t)vi*49152;
    biP = vbih + (size_t)vi*384;  bhP = vbhh + (size_t)vi*384;
    ho = h2 + (size_t)s*48*128;
  }

  int w = threadIdx.x >> 6, l = threadIdx.x & 63;
  int lr = l & 15, lq = l >> 4;

  bf8 wfi[3][4], wfh[3][4];
  #pragma unroll
  for (int j = 0; j < 3; ++j){
    int colb = (w + 8*j)*16;
    const u16* wpi = Wi + (size_t)(colb + lr)*128 + lq*8;
    const u16* wph = Wh + (size_t)(colb + lr)*128 + lq*8;
    #pragma unroll
    for (int kt = 0; kt < 4; ++kt){
      wfi[j][kt] = *(const bf8*)(wpi + kt*32);
      wfh[j][kt] = *(const bf8*)(wph + kt*32);
    }
  }
  float bs0_ = -LOG2E*(biP[w*16 + lr]     + bhP[w*16 + lr]);
  float bs1_ = -LOG2E*(biP[(8+w)*16 + lr] + bhP[(8+w)*16 + lr]);
  float bin_ =  TWOL*biP[(16+w)*16 + lr];
  float bhn_ =  TWOL*bhP[(16+w)*16 + lr];

  const u16* ap = A + (size_t)(g*16 + lr)*128 + lq*8;
  __shared__ u16 hlds[2][16][132];   // 66-dword row stride: conflict-free b128
  float hp[4] = {0.f,0.f,0.f,0.f};
  int cur = 0;
  f4 ANr;

  if (rstride){
    bf8 S0[4], S1[4];
    f4 gE0,gE1,gE2, gO0,gO1,gO2;
    ALOAD(S0,0); ALOAD(S1,1);
    GIMM(gE0,gE1,gE2,S0); ALOAD(S0,2);
    GIMM(gO0,gO1,gO2,S1); ALOAD(S1,3);
    { f4 an0={bhn_,bhn_,bhn_,bhn_}; ANr=an0;
      GATES(gE0,gE1,gE2,ANr); }               // t=0 (h0=0)
    GIMM(gE0,gE1,gE2,S0); ALOAD(S0,4);
    STEPB(gO0,gO1,gO2,S1,1);
    for (int t = 2; t < T; t += 2){
      STEPB(gE0,gE1,gE2,S0,t);
      STEPB(gO0,gO1,gO2,S1,t+1);
    }
  } else {
    f4 C0,C1,C2;
    { bf8 S0[4]; ALOAD(S0,0); GIMM(C0,C1,C2,S0); }   // constant gi
    { f4 an0={bhn_,bhn_,bhn_,bhn_}; ANr=an0;
      GATES(C0,C1,C2,ANr); }                  // t=0
    for (int t = 1; t < T; ++t){
      f4 G0=C0, G1=C1;
      GH(G0,G1,ANr);
      GATES(G0,G1,C2,ANr);
    }
  }

  if (oMode == 0){
    #pragma unroll
    for (int r = 0; r < 4; ++r)
      ho[((size_t)(lq*4+r)*48 + g)*128 + w*16 + lr] = f2bf(hp[r]);
  } else {
    #pragma unroll
    for (int r = 0; r < 4; ++r)
      ho[((size_t)(g*16 + lq*4 + r))*128 + w*16 + lr] = f2bf(hp[r]);
  }
}

// ================= final projection =================
__global__ __launch_bounds__(256) void k_final(const u16* __restrict__ h2,
                                               const float* __restrict__ W,
                                               const float* __restrict__ Bias,
                                               float* __restrict__ out){
  int b = blockIdx.x, t = threadIdx.x;
  __shared__ float emb[896];
  for (int i = t; i < 896; i += 256){
    int j = i >> 7, d = i & 127;
    float v = bf2f(h2[((size_t)j*48 + b)*128 + d]);
    if (j >= 1 && j <= 3) v *= 2.0f;   // slots 1..3 appear twice in reference sum
    emb[i] = fmaxf(v, 0.f);
  }
  __syncthreads();
  float acc = Bias[t];
  const float* wp = W + (size_t)t*896;
  for (int i = 0; i < 896; i += 8){
    float4 w0 = *(const float4*)(wp + i);
    float4 w1 = *(const float4*)(wp + i + 4);
    acc += w0.x*emb[i]   + w0.y*emb[i+1] + w0.z*emb[i+2] + w0.w*emb[i+3];
    acc += w1.x*emb[i+4] + w1.y*emb[i+5] + w1.z*emb[i+6] + w1.w*emb[i+7];
  }
  out[(size_t)b*256 + t] = acc;
}

extern "C" void kernel_launch(void* const* d_in, const int* in_sizes, int n_in,
                              void* d_out, int out_size, void* d_ws, size_t ws_size,
                              hipStream_t stream){
  const int*   visit_ids   = (const int*)d_in[0];
  const int*   mon_ids     = (const int*)d_in[1];
  const float* weight_vals = (const float*)d_in[2];
  const float* age_vals    = (const float*)d_in[3];
  const float* emb_visit   = (const float*)d_in[4];
  const float* emb_mon     = (const float*)d_in[5];
  const float* mgru_Wih    = (const float*)d_in[6];
  const float* mgru_Whh    = (const float*)d_in[7];
  const float* mgru_bih    = (const float*)d_in[8];
  const float* mgru_bhh    = (const float*)d_in[9];
  const float* vgru_Wih    = (const float*)d_in[10];
  const float* vgru_Whh    = (const float*)d_in[11];
  const float* vgru_bih    = (const float*)d_in[12];
  const float* vgru_bhh    = (const float*)d_in[13];
  const float* fc_w_w      = (const float*)d_in[14];
  const float* fc_w_b      = (const float*)d_in[15];
  const float* fc_a_w      = (const float*)d_in[16];
  const float* fc_a_b      = (const float*)d_in[17];
  const float* fc_out_w    = (const float*)d_in[18];
  const float* fc_out_b    = (const float*)d_in[19];

  char* ws = (char*)d_ws;
  size_t o = 0;
  u16* mWih_b  = (u16*)(ws+o); o += 5ull*384*128*2;
  u16* mWhh_b  = (u16*)(ws+o); o += 5ull*384*128*2;
  u16* vWih_b  = (u16*)(ws+o); o += 7ull*384*128*2;
  u16* vWhh_b  = (u16*)(ws+o); o += 7ull*384*128*2;
  u16* embm_b  = (u16*)(ws+o); o += 4ull*1000*128*2;
  u16* embv_b  = (u16*)(ws+o); o += 3ull*2000*128*2;
  u16* mon_xT  = (u16*)(ws+o); o += 2ull*24576*128*2;    // [p][m*768+bv][128]
  u16* vis_org = (u16*)(ws+o); o += 3ull*768*128*2;
  u16* hin2T   = (u16*)(ws+o); o += 7ull*768*128*2;      // [slot][v*48+b][128]
  u16* h2      = (u16*)(ws+o); o += 7ull*48*128*2;       // ~19 MB total

  k_prep<<<2402, 256, 0, stream>>>(mgru_Wih, mgru_Whh, vgru_Wih, vgru_Whh, emb_mon, emb_visit,
                                   mWih_b, mWhh_b, vWih_b, vWhh_b, embm_b, embv_b);
  k_bags<<<dim3(1536,3), 256, 0, stream>>>(visit_ids, mon_ids, embv_b, embm_b,
      weight_vals, age_vals, fc_w_w, fc_w_b, fc_a_w, fc_a_b,
      mon_xT, vis_org, hin2T);
  // phase 0: monitor-level streams 0..4 (240 blocks <= 256 CUs)
  k_gru<<<dim3(48,5), 512, 0, stream>>>(0, mon_xT, vis_org, hin2T, h2,
      mWih_b, mgru_bih, mWhh_b, mgru_bhh, vWih_b, vgru_bih, vWhh_b, vgru_bhh);
  // phase 1: visit-level streams 0..6
  k_gru<<<dim3(3,7), 512, 0, stream>>>(1, mon_xT, vis_org, hin2T, h2,
      mWih_b, mgru_bih, mWhh_b, mgru_bhh, vWih_b, vgru_bih, vWhh_b, vgru_bhh);
  k_final<<<48, 256, 0, stream>>>(h2, fc_out_w, fc_out_b, (float*)d_out);
}